// Round 2
// baseline (10849.818 us; speedup 1.0000x reference)
//
#include <hip/hip_runtime.h>
#include <hip/hip_bf16.h>

// GPT_90202903150925 — 4-layer GPT forward on gfx950.
// Round 2: dtype fix. Inputs are FLOAT32 (per harness rule), output FLOAT32.
//   - weights converted f32->bf16 during the one-time transpose pass
//   - residual stream h kept in f32 in ws; activations bf16 for MFMA
//   - GEMM: 128x128 tile, BK=32, mfma_f32_16x16x32_bf16, padded LDS
//   - attention: wave-per-query-row online softmax, 4-key unroll

typedef __hip_bfloat16 bf16;
typedef __attribute__((ext_vector_type(8))) short short8;
typedef __attribute__((ext_vector_type(4))) float floatx4;

#define Bsz 2
#define Lseq 2048
#define Dmod 512
#define NHn 8
#define NLn 4
#define DMn 2048
#define Vn 32000
#define HDn 64
#define Mrows 4096  // B*L

// ------------- transpose+cast: src_f32[R][C] -> dst_bf16[C][R] -------------
__global__ void transpose_kernel(const float* __restrict__ src, bf16* __restrict__ dst,
                                 int R, int C) {
    __shared__ float tile[32][33];
    int c0 = blockIdx.x * 32, r0 = blockIdx.y * 32;
    int tx = threadIdx.x, ty = threadIdx.y;  // block (32,8)
    #pragma unroll
    for (int i = 0; i < 32; i += 8)
        tile[ty + i][tx] = src[(long)(r0 + ty + i) * C + (c0 + tx)];
    __syncthreads();
    #pragma unroll
    for (int i = 0; i < 32; i += 8)
        dst[(long)(c0 + ty + i) * R + (r0 + tx)] = (bf16)tile[tx][ty + i];
}

// ---------------- embedding: h = tok_emb[x] + pos_emb (all f32) ----------------
__global__ __launch_bounds__(256) void embed_kernel(const int* __restrict__ x,
                                                    const float* __restrict__ tok,
                                                    const float* __restrict__ pos,
                                                    float* __restrict__ h) {
    int row = blockIdx.x;            // b*L + l
    int l = row & (Lseq - 1);
    int t = x[row];
    int d = threadIdx.x;
    #pragma unroll
    for (int i = 0; i < Dmod; i += 256) {
        int c = d + i;
        h[(long)row * Dmod + c] = tok[(long)t * Dmod + c] + pos[(long)l * Dmod + c];
    }
}

// ---------------- layernorm: out_bf16 = LN(h_f32)*g + b (g,b f32) ----------------
__global__ __launch_bounds__(256) void ln_kernel(const float* __restrict__ h,
                                                 const float* __restrict__ g,
                                                 const float* __restrict__ b,
                                                 bf16* __restrict__ out) {
    int wave = threadIdx.x >> 6, lane = threadIdx.x & 63;
    int row = blockIdx.x * 4 + wave;
    const float* hr = h + (long)row * Dmod;
    float v[8];
    float s = 0.f;
    #pragma unroll
    for (int i = 0; i < 8; i++) { v[i] = hr[i * 64 + lane]; s += v[i]; }
    #pragma unroll
    for (int o = 32; o > 0; o >>= 1) s += __shfl_xor(s, o, 64);
    float mu = s * (1.0f / Dmod);
    float sq = 0.f;
    #pragma unroll
    for (int i = 0; i < 8; i++) { float d0 = v[i] - mu; sq += d0 * d0; }
    #pragma unroll
    for (int o = 32; o > 0; o >>= 1) sq += __shfl_xor(sq, o, 64);
    float rstd = rsqrtf(sq * (1.0f / Dmod) + 1e-5f);
    #pragma unroll
    for (int i = 0; i < 8; i++) {
        int c = i * 64 + lane;
        out[(long)row * Dmod + c] = (bf16)((v[i] - mu) * rstd * g[c] + b[c]);
    }
}

// ---------------- GEMM: C[M,N] = A[M,K] @ B[K,N] (+bias f32), B given as BT[N,K]
// MODE 0: store bf16; MODE 1: gelu(exact)->bf16; MODE 2: h_f32 += C; MODE 3: store f32
template <int MODE>
__global__ __launch_bounds__(256) void gemm_kernel(const bf16* __restrict__ A,
                                                   const bf16* __restrict__ BT,
                                                   const float* __restrict__ bias,
                                                   float* __restrict__ h,
                                                   bf16* __restrict__ outb,
                                                   float* __restrict__ outf,
                                                   int N, int K) {
    __shared__ __align__(16) short As[128][40];  // +8 pad: 2-way banks only (free)
    __shared__ __align__(16) short Bs[128][40];
    const int tid = threadIdx.x;
    const int wave = tid >> 6, lane = tid & 63;
    const int bm = blockIdx.y, bn = blockIdx.x;
    const int wm = (wave >> 1) * 64, wn = (wave & 1) * 64;
    const int quad = lane >> 4, l16 = lane & 15;

    floatx4 acc[4][4] = {};

    const int r0 = tid >> 2;          // 0..63
    const int kc = (tid & 3) * 8;     // 0,8,16,24
    const long arow0 = (long)(bm * 128 + r0) * K;
    const long arow1 = (long)(bm * 128 + 64 + r0) * K;
    const long brow0 = (long)(bn * 128 + r0) * K;
    const long brow1 = (long)(bn * 128 + 64 + r0) * K;

    for (int k0 = 0; k0 < K; k0 += 32) {
        __syncthreads();
        *(float4*)&As[r0][kc]      = *(const float4*)(A + arow0 + k0 + kc);
        *(float4*)&As[64 + r0][kc] = *(const float4*)(A + arow1 + k0 + kc);
        *(float4*)&Bs[r0][kc]      = *(const float4*)(BT + brow0 + k0 + kc);
        *(float4*)&Bs[64 + r0][kc] = *(const float4*)(BT + brow1 + k0 + kc);
        __syncthreads();
        short8 af[4], bfr[4];
        #pragma unroll
        for (int t = 0; t < 4; t++) {
            af[t]  = *(const short8*)&As[wm + t * 16 + l16][quad * 8];
            bfr[t] = *(const short8*)&Bs[wn + t * 16 + l16][quad * 8];
        }
        #pragma unroll
        for (int mt = 0; mt < 4; mt++)
            #pragma unroll
            for (int nt = 0; nt < 4; nt++)
                acc[mt][nt] = __builtin_amdgcn_mfma_f32_16x16x32_bf16(af[mt], bfr[nt], acc[mt][nt], 0, 0, 0);
    }

    #pragma unroll
    for (int mt = 0; mt < 4; mt++) {
        int row = bm * 128 + wm + mt * 16 + quad * 4;
        #pragma unroll
        for (int nt = 0; nt < 4; nt++) {
            int col = bn * 128 + wn + nt * 16 + l16;
            float bv = bias ? bias[col] : 0.0f;
            #pragma unroll
            for (int r = 0; r < 4; r++) {
                float c = acc[mt][nt][r] + bv;
                long off = (long)(row + r) * N + col;
                if (MODE == 0) {
                    outb[off] = (bf16)c;
                } else if (MODE == 1) {
                    float gl = 0.5f * c * (1.0f + erff(c * 0.70710678118f));
                    outb[off] = (bf16)gl;
                } else if (MODE == 2) {
                    h[off] += c;
                } else {
                    outf[off] = c;
                }
            }
        }
    }
}

// ---------------- attention: wave per query row, online softmax ----------------
__global__ __launch_bounds__(256) void attn_kernel(const bf16* __restrict__ qkv,
                                                   bf16* __restrict__ o) {
    int wave = threadIdx.x >> 6, lane = threadIdx.x & 63;
    long idx = (long)blockIdx.x * 4 + wave;  // (b*NH + h)*L + q
    int q = (int)(idx & (Lseq - 1));
    int bh = (int)(idx >> 11);
    int b = bh >> 3, hh = bh & 7;

    const bf16* qrow  = qkv + (long)(b * Lseq + q) * (3 * Dmod) + hh * HDn;
    const bf16* kbase = qkv + (long)b * Lseq * 3 * Dmod + Dmod + hh * HDn;
    const bf16* vbase = kbase + Dmod;

    float qd = (float)qrow[lane] * 0.125f;  // 1/sqrt(64)

    float m = -1e30f, l_sum = 0.f, o_acc = 0.f;
    for (int k0 = 0; k0 <= q; k0 += 4) {
        float s[4];
        #pragma unroll
        for (int i = 0; i < 4; i++) {
            int k = k0 + i;
            int kk = (k <= q) ? k : q;
            float kv = (float)kbase[(long)kk * (3 * Dmod) + lane];
            float p = qd * kv;
            #pragma unroll
            for (int off = 32; off > 0; off >>= 1) p += __shfl_xor(p, off, 64);
            s[i] = (k <= q) ? p : -1e30f;
        }
        float mb = m;
        #pragma unroll
        for (int i = 0; i < 4; i++) mb = fmaxf(mb, s[i]);
        float alpha = __expf(m - mb);
        float esum = 0.f, vsum = 0.f;
        #pragma unroll
        for (int i = 0; i < 4; i++) {
            int k = k0 + i;
            int kk = (k <= q) ? k : q;
            float e = __expf(s[i] - mb);  // 0 for invalid lanes (s=-1e30)
            float vv = (float)vbase[(long)kk * (3 * Dmod) + lane];
            esum += e;
            vsum += e * vv;
        }
        l_sum = l_sum * alpha + esum;
        o_acc = o_acc * alpha + vsum;
        m = mb;
    }
    o[(long)(b * Lseq + q) * Dmod + hh * HDn + lane] = (bf16)(o_acc / l_sum);
}

// ---------------- host launch ----------------
extern "C" void kernel_launch(void* const* d_in, const int* in_sizes, int n_in,
                              void* d_out, int out_size, void* d_ws, size_t ws_size,
                              hipStream_t stream) {
    const int*   x      = (const int*)d_in[0];
    const float* tok    = (const float*)d_in[1];
    const float* pos    = (const float*)d_in[2];
    const float* ln1_g  = (const float*)d_in[3];
    const float* ln1_b  = (const float*)d_in[4];
    const float* qkv_w  = (const float*)d_in[5];
    const float* qkv_b  = (const float*)d_in[6];
    const float* out_w  = (const float*)d_in[7];
    const float* out_b  = (const float*)d_in[8];
    const float* ln2_g  = (const float*)d_in[9];
    const float* ln2_b  = (const float*)d_in[10];
    const float* w1     = (const float*)d_in[11];
    const float* b1     = (const float*)d_in[12];
    const float* w2     = (const float*)d_in[13];
    const float* b2     = (const float*)d_in[14];
    const float* lnf_g  = (const float*)d_in[15];
    const float* lnf_b  = (const float*)d_in[16];
    const float* head_w = (const float*)d_in[17];
    float* out = (float*)d_out;

    char* w = (char*)d_ws;
    float* h      = (float*)(w + 0);              // 4096x512 f32    =  8,388,608
    bf16*  lnbuf  = (bf16*)(w + 8388608);         // 4096x512 bf16   =  4,194,304
    bf16*  qkvbuf = (bf16*)(w + 12582912);        // 4096x1536 bf16  = 12,582,912
    bf16*  attn_o = (bf16*)(w + 25165824);        // 4096x512 bf16   =  4,194,304
    bf16*  mlpbuf = (bf16*)(w + 29360128);        // 4096x2048 bf16  = 16,777,216
    bf16*  qkvT   = (bf16*)(w + 46137344);        // 4x1536x512      =  6,291,456
    bf16*  outT   = (bf16*)(w + 52428800);        // 4x512x512       =  2,097,152
    bf16*  w1T    = (bf16*)(w + 54525952);        // 4x2048x512      =  8,388,608
    bf16*  w2T    = (bf16*)(w + 62914560);        // 4x512x2048      =  8,388,608
    bf16*  headT  = (bf16*)(w + 71303168);        // 32000x512       = 32,768,000
    // total ws need: 104,071,168 bytes

    dim3 tb(32, 8);
    for (int l = 0; l < NLn; l++) {
        transpose_kernel<<<dim3(3 * Dmod / 32, Dmod / 32), tb, 0, stream>>>(
            qkv_w + (long)l * Dmod * 3 * Dmod, qkvT + (long)l * 3 * Dmod * Dmod, Dmod, 3 * Dmod);
        transpose_kernel<<<dim3(Dmod / 32, Dmod / 32), tb, 0, stream>>>(
            out_w + (long)l * Dmod * Dmod, outT + (long)l * Dmod * Dmod, Dmod, Dmod);
        transpose_kernel<<<dim3(DMn / 32, Dmod / 32), tb, 0, stream>>>(
            w1 + (long)l * Dmod * DMn, w1T + (long)l * DMn * Dmod, Dmod, DMn);
        transpose_kernel<<<dim3(Dmod / 32, DMn / 32), tb, 0, stream>>>(
            w2 + (long)l * DMn * Dmod, w2T + (long)l * Dmod * DMn, DMn, Dmod);
    }
    transpose_kernel<<<dim3(Vn / 32, Dmod / 32), tb, 0, stream>>>(head_w, headT, Dmod, Vn);

    embed_kernel<<<Mrows, 256, 0, stream>>>(x, tok, pos, h);

    for (int l = 0; l < NLn; l++) {
        ln_kernel<<<Mrows / 4, 256, 0, stream>>>(h, ln1_g + l * Dmod, ln1_b + l * Dmod, lnbuf);
        gemm_kernel<0><<<dim3(3 * Dmod / 128, Mrows / 128), 256, 0, stream>>>(
            lnbuf, qkvT + (long)l * 3 * Dmod * Dmod, qkv_b + l * 3 * Dmod, nullptr, qkvbuf,
            nullptr, 3 * Dmod, Dmod);
        attn_kernel<<<(Bsz * NHn * Lseq) / 4, 256, 0, stream>>>(qkvbuf, attn_o);
        gemm_kernel<2><<<dim3(Dmod / 128, Mrows / 128), 256, 0, stream>>>(
            attn_o, outT + (long)l * Dmod * Dmod, out_b + l * Dmod, h, nullptr, nullptr,
            Dmod, Dmod);
        ln_kernel<<<Mrows / 4, 256, 0, stream>>>(h, ln2_g + l * Dmod, ln2_b + l * Dmod, lnbuf);
        gemm_kernel<1><<<dim3(DMn / 128, Mrows / 128), 256, 0, stream>>>(
            lnbuf, w1T + (long)l * DMn * Dmod, b1 + l * DMn, nullptr, mlpbuf, nullptr,
            DMn, Dmod);
        gemm_kernel<2><<<dim3(Dmod / 128, Mrows / 128), 256, 0, stream>>>(
            mlpbuf, w2T + (long)l * Dmod * DMn, b2 + l * Dmod, h, nullptr, nullptr,
            Dmod, DMn);
    }
    ln_kernel<<<Mrows / 4, 256, 0, stream>>>(h, lnf_g, lnf_b, lnbuf);
    gemm_kernel<3><<<dim3(Vn / 128, Mrows / 128), 256, 0, stream>>>(
        lnbuf, headT, nullptr, nullptr, nullptr, out, Vn, Dmod);
}